// Round 13
// baseline (3134.498 us; speedup 1.0000x reference)
//
#include <hip/hip_runtime.h>
#include <hip/hip_bf16.h>

// ============================================================================
// PPO agent fused forward (round 13):
//  r10/r12 post-mortem: 256-thr + ~30 block barriers => ~334 dwords/thread
//  scratch spill (WRITE 2.845 GB, byte-identical across different staging
//  code); the spill traffic IS the 2.2ms. r7 (128-thr, barrier-free) was the
//  only near-spill-free shape.
//  This round: per-wave PRIVATE DMA double-buffering, no barriers at all.
//   - each wave global_load_lds's its own 8KB B-chunks into its own LDS slice
//     (zero landing regs); sync = the wave's own s_waitcnt vmcnt(0), placed
//     BEFORE issuing the next chunk -> chunk n+1 DMA flies during chunk n
//     compute.
//   - ws weights pre-permuted to ntile/fragment-major (16-col tiles, 1KB per
//     k-slice, lane l bytes l*16): linear DMA image == read order ->
//     conflict-free ds_read_b128 at base + ks*1024 + lane*16.
//   - pre-LN stash via ds_write_b16 into the same swizzled ACT layout that
//     build_frags reads (identical rounding -> identical numerics).
//  Per-wave regs ~85 < 128; LDS 48KB/block(128thr) -> 3 blocks/CU.
// ============================================================================

#define T_SZ 524288
#define GL 0.9405f   // GAMMA*LAM

typedef __attribute__((ext_vector_type(8))) short bf16x8;   // 8 bf16 (4 VGPRs)
typedef __attribute__((ext_vector_type(4))) float f32x4;
typedef __attribute__((address_space(1))) const void* gas_t;
typedef __attribute__((address_space(3))) void* las_t;

// ws layout (bf16 elements); weights in ntile/fragment-major layout
#define OFF_AW1T 0        // 256x64
#define OFF_AW2T 16384    // 256x256
#define OFF_AW3T 81920    // 32x256 (rows >=18 zero)
#define OFF_CW1T 90112    // 256x64
#define OFF_CW2T 106496   // 256x256
#define OFF_CW3T 172032   // 16x256 (rows >=1 zero)
#define W_ELEMS  176128
#define OFF_DELTAS_BYTES 352256

// k = p*32 + h*16 + w -> pos = p*32 + w*2 + h (applied to A and B alike)
__device__ __forceinline__ int perm_k(int k) {
  return (k & ~31) | ((k & 15) << 1) | ((k >> 4) & 1);
}

__device__ __forceinline__ unsigned pack2(float a, float b) {
  union { __hip_bfloat16 h; unsigned short u; } ua, ub;
  ua.h = __float2bfloat16(a); ub.h = __float2bfloat16(b);
  return (unsigned)ua.u | ((unsigned)ub.u << 16);
}

__device__ __forceinline__ void unpack2(unsigned u, float& a, float& b) {
  union { unsigned u; float f; } x, y;
  x.u = u << 16; y.u = u & 0xFFFF0000u;
  a = x.f; b = y.f;
}

// per-wave ACT accessor (stride 512B, 16B-granular XOR on row&7)
__device__ __forceinline__ void* act_at(void* base, int row, int colByte) {
  return (char*)base + row * 512 + (colByte ^ ((row & 7) << 4));
}

#define VMWAIT() asm volatile("s_waitcnt vmcnt(0)" ::: "memory")

// per-wave DMA: NSEG KB from global src to this wave's LDS dst (linear).
template<int NSEG>
__device__ __forceinline__ void dma(const char* __restrict__ src, char* dst, int lane) {
#pragma unroll
  for (int s2 = 0; s2 < NSEG; ++s2)
    __builtin_amdgcn_global_load_lds((gas_t)(src + s2 * 1024 + lane * 16),
                                     (las_t)(dst + s2 * 1024), 16, 0, 0);
}

// ---------------------------------------------------------------------------
// X tile (16 rows x 64 fp32) -> 2 k-permuted bf16x8 frags per lane.
__device__ __forceinline__ void load_x_frags(const float* __restrict__ src,
                                             int c, int q, bf16x8* xf) {
  const float* rp = src + (size_t)c * 64;
#pragma unroll
  for (int ks = 0; ks < 2; ++ks) {
    float4 a = *(const float4*)(rp + ks * 32 + 4 * q);
    float4 b = *(const float4*)(rp + ks * 32 + 4 * q + 16);
    unsigned u[4];
    u[0] = pack2(a.x, b.x); u[1] = pack2(a.y, b.y);
    u[2] = pack2(a.z, b.z); u[3] = pack2(a.w, b.w);
    xf[ks] = *(bf16x8*)u;
  }
}

// shared LN tail: reduce s/ss, broadcast row-c stats -> (mc, rc)
__device__ __forceinline__ void ln_stats(float* s, float* ss, int c,
                                         float& mc, float& rc) {
#pragma unroll
  for (int m = 1; m < 16; m <<= 1) {
#pragma unroll
    for (int r = 0; r < 4; ++r) {
      s[r]  += __shfl_xor(s[r],  m, 64);
      ss[r] += __shfl_xor(ss[r], m, 64);
    }
  }
  float mean[4], rs[4];
#pragma unroll
  for (int r = 0; r < 4; ++r) {
    mean[r] = s[r] * (1.f / 256.f);
    float var = ss[r] * (1.f / 256.f) - mean[r] * mean[r];
    rs[r] = rsqrtf(var + 1e-5f);
  }
  const int srcLane = ((c >> 2) << 4) + c;
  float mb[4], rb[4];
#pragma unroll
  for (int r = 0; r < 4; ++r) {
    mb[r] = __shfl(mean[r], srcLane, 64);
    rb[r] = __shfl(rs[r],   srcLane, 64);
  }
  const float m01 = (c & 1) ? mb[1] : mb[0], m23 = (c & 1) ? mb[3] : mb[2];
  const float r01 = (c & 1) ? rb[1] : rb[0], r23 = (c & 1) ? rb[3] : rb[2];
  mc = (c & 2) ? m23 : m01;
  rc = (c & 2) ? r23 : r01;
}

// build next-layer frags from pre-LN ACT (normalize+ReLU in regs)
__device__ __forceinline__ void build_frags(void* ACT,
    const float* __restrict__ gam, const float* __restrict__ bet,
    float mc, float rc, int c, int q, bf16x8* of) {
#pragma unroll
  for (int ks = 0; ks < 8; ++ks) {
    uint4 dv = *(const uint4*)act_at(ACT, c, ks * 64 + q * 16);
    unsigned w[4];
    const unsigned* dp = (const unsigned*)&dv;
#pragma unroll
    for (int i = 0; i < 4; ++i) {
      const int n0 = ks * 32 + q * 4 + i;
      float v0, v1;
      unpack2(dp[i], v0, v1);
      float w0 = fmaxf((v0 - mc) * rc * gam[n0]      + bet[n0],      0.f);
      float w1 = fmaxf((v1 - mc) * rc * gam[n0 + 16] + bet[n0 + 16], 0.f);
      w[i] = pack2(w0, w1);
    }
    of[ks] = *(bf16x8*)w;
  }
}

// per-ntile epilogue: bias add, s/ss accumulate, pre-LN bf16 stash (b16)
__device__ __forceinline__ void ntile_epi(const f32x4& acc, float bb,
    float* s, float* ss, void* ACT, int nt, int c, int q) {
  const int kpn = ((nt >> 1) << 5) + (c << 1) + (nt & 1);
#pragma unroll
  for (int r = 0; r < 4; ++r) {
    float v = acc[r] + bb;
    s[r] += v; ss[r] += v * v;
    const int row = q * 4 + r;
    *(__hip_bfloat16*)((char*)ACT + row * 512 + ((kpn * 2) ^ ((row & 7) << 4)))
        = __float2bfloat16(v);
  }
}

// ---------------------------------------------------------------------------
// K=64 layer (Linear+LN+ReLU): 4 chunks of 4 ntiles (8KB), per-wave dbuf DMA.
__device__ __forceinline__ void layer64(const bf16x8* xf,
    const char* __restrict__ W,
    const float* __restrict__ bias, const float* __restrict__ gam,
    const float* __restrict__ bet, char* ACT, char* B0, char* B1,
    int c, int q, int lane, bf16x8* of) {
  dma<8>(W, B0, lane);
  float s[4] = {0, 0, 0, 0}, ss[4] = {0, 0, 0, 0};
#pragma unroll
  for (int ch = 0; ch < 4; ++ch) {
    char* cur = (ch & 1) ? B1 : B0;
    char* nxt = (ch & 1) ? B0 : B1;
    VMWAIT();
    if (ch < 3) dma<8>(W + (ch + 1) * 8192, nxt, lane);
#pragma unroll
    for (int t = 0; t < 4; ++t) {
      const int nt = ch * 4 + t;
      f32x4 acc = {0.f, 0.f, 0.f, 0.f};
#pragma unroll
      for (int ks = 0; ks < 2; ++ks) {
        bf16x8 b = *(const bf16x8*)(cur + t * 2048 + ks * 1024 + lane * 16);
        acc = __builtin_amdgcn_mfma_f32_16x16x32_bf16(xf[ks], b, acc, 0, 0, 0);
      }
      ntile_epi(acc, bias[nt * 16 + c], s, ss, ACT, nt, c, q);
    }
  }
  float mc, rc;
  ln_stats(s, ss, c, mc, rc);
  build_frags(ACT, gam, bet, mc, rc, c, q, of);
}

// K=256 layer (Linear+LN+ReLU): 16 ntile chunks (8KB each), per-wave dbuf DMA.
__device__ __forceinline__ void layer256(const bf16x8* af,
    const char* __restrict__ W,
    const float* __restrict__ bias, const float* __restrict__ gam,
    const float* __restrict__ bet, char* ACT, char* B0, char* B1,
    int c, int q, int lane, bf16x8* of) {
  dma<8>(W, B0, lane);
  float s[4] = {0, 0, 0, 0}, ss[4] = {0, 0, 0, 0};
#pragma unroll
  for (int nt = 0; nt < 16; ++nt) {
    char* cur = (nt & 1) ? B1 : B0;
    char* nxt = (nt & 1) ? B0 : B1;
    VMWAIT();
    if (nt < 15) dma<8>(W + (size_t)(nt + 1) * 8192, nxt, lane);
    f32x4 acc = {0.f, 0.f, 0.f, 0.f};
#pragma unroll
    for (int ks = 0; ks < 8; ++ks) {
      bf16x8 b = *(const bf16x8*)(cur + ks * 1024 + lane * 16);
      acc = __builtin_amdgcn_mfma_f32_16x16x32_bf16(af[ks], b, acc, 0, 0, 0);
    }
    ntile_epi(acc, bias[nt * 16 + c], s, ss, ACT, nt, c, q);
  }
  float mc, rc;
  ln_stats(s, ss, c, mc, rc);
  build_frags(ACT, gam, bet, mc, rc, c, q, of);
}

// small final GEMM: NT ntiles, K=256, per-wave DMA pipelined
template<int NT>
__device__ __forceinline__ void run_small(const bf16x8* af,
    const char* __restrict__ W, char* B0, char* B1,
    int c, int q, int lane, f32x4* acc) {
  dma<8>(W, B0, lane);
#pragma unroll
  for (int nt = 0; nt < NT; ++nt) {
    char* cur = (nt & 1) ? B1 : B0;
    char* nxt = (nt & 1) ? B0 : B1;
    VMWAIT();
    if (nt + 1 < NT) dma<8>(W + (nt + 1) * 8192, nxt, lane);
    acc[nt] = (f32x4){0.f, 0.f, 0.f, 0.f};
#pragma unroll
    for (int ks = 0; ks < 8; ++ks) {
      bf16x8 b = *(const bf16x8*)(cur + ks * 1024 + lane * 16);
      acc[nt] = __builtin_amdgcn_mfma_f32_16x16x32_bf16(af[ks], b, acc[nt], 0, 0, 0);
    }
  }
}

__device__ __forceinline__ void softmax_write(f32x4* acc3,
    const float* __restrict__ ab3, float* __restrict__ out,
    int grow0, int c, int q) {
  float b0 = ab3[c];
  float b1 = (c < 2) ? ab3[16 + c] : 0.f;
#pragma unroll
  for (int r = 0; r < 4; ++r) {
    float x0 = acc3[0][r] + b0;
    float x1 = (c < 2) ? (acc3[1][r] + b1) : -1e30f;
    float mx = fmaxf(x0, x1);
#pragma unroll
    for (int m = 1; m < 16; m <<= 1) mx = fmaxf(mx, __shfl_xor(mx, m, 64));
    float e0 = __expf(x0 - mx);
    float e1 = (c < 2) ? __expf(x1 - mx) : 0.f;
    float sm = e0 + e1;
#pragma unroll
    for (int m = 1; m < 16; m <<= 1) sm += __shfl_xor(sm, m, 64);
    float inv = 1.f / sm;
    int gr = grow0 + q * 4 + r;
    out[(size_t)gr * 20 + c] = e0 * inv;
    if (c < 2) out[(size_t)gr * 20 + 16 + c] = e1 * inv;
  }
}

// ---------------------------------------------------------------------------
// prep: ntile/fragment-major layout. For weight (n,k) of an [N][K] matrix:
// nt=n>>4, cc=n&15; kp=perm_k(k): ks=kp>>5, q=(kp&31)>>3, e=kp&7
// -> elem = MO + nt*(16*K) + ks*512 + (q*16+cc)*8 + e.
__device__ __forceinline__ int frag_idx(int mo, int K, int n, int k) {
  const int kp = perm_k(k);
  const int nt = n >> 4, cc = n & 15;
  const int ks = kp >> 5, w = kp & 31, qq = w >> 3, e = w & 7;
  return mo + nt * (16 * K) + ks * 512 + (qq * 16 + cc) * 8 + e;
}

__global__ void prep_weights(const float* __restrict__ aw1, const float* __restrict__ aw2,
                             const float* __restrict__ aw3, const float* __restrict__ cw1,
                             const float* __restrict__ cw2, const float* __restrict__ cw3,
                             __hip_bfloat16* __restrict__ wb) {
  int i = blockIdx.x * 256 + threadIdx.x;
  if (i >= W_ELEMS) return;
  float v; int dst;
  if (i < OFF_AW2T)      { int j = i;            int n = j >> 6, k = j & 63;  v = aw1[k * 256 + n];                 dst = frag_idx(OFF_AW1T, 64,  n, k); }
  else if (i < OFF_AW3T) { int j = i - OFF_AW2T; int n = j >> 8, k = j & 255; v = aw2[k * 256 + n];                 dst = frag_idx(OFF_AW2T, 256, n, k); }
  else if (i < OFF_CW1T) { int j = i - OFF_AW3T; int n = j >> 8, k = j & 255; v = (n < 18) ? aw3[k * 18 + n] : 0.f; dst = frag_idx(OFF_AW3T, 256, n, k); }
  else if (i < OFF_CW2T) { int j = i - OFF_CW1T; int n = j >> 6, k = j & 63;  v = cw1[k * 256 + n];                 dst = frag_idx(OFF_CW1T, 64,  n, k); }
  else if (i < OFF_CW3T) { int j = i - OFF_CW2T; int n = j >> 8, k = j & 255; v = cw2[k * 256 + n];                 dst = frag_idx(OFF_CW2T, 256, n, k); }
  else                   { int j = i - OFF_CW3T; int n = j >> 8, k = j & 255; v = (n == 0) ? cw3[k] : 0.f;          dst = frag_idx(OFF_CW3T, 256, n, k); }
  wb[dst] = __float2bfloat16(v);
}

// ---------------------------------------------------------------------------
__global__ __launch_bounds__(128, 2) void mlp_kernel(
    const float* __restrict__ states, const float* __restrict__ next_states,
    const float* __restrict__ rewards, const float* __restrict__ masks,
    const float* __restrict__ ab1, const float* __restrict__ ag1, const float* __restrict__ an1,
    const float* __restrict__ ab2, const float* __restrict__ ag2, const float* __restrict__ an2,
    const float* __restrict__ ab3,
    const float* __restrict__ cb1, const float* __restrict__ cg1, const float* __restrict__ cn1,
    const float* __restrict__ cb2, const float* __restrict__ cg2, const float* __restrict__ cn2,
    const float* __restrict__ cb3,
    const __hip_bfloat16* __restrict__ wbuf,
    float* __restrict__ deltas, float* __restrict__ out) {
  __shared__ char LB[2][24576];       // per wave: B0 8K | B1 8K | ACT 8K
  const int tid = threadIdx.x;
  const int wave = tid >> 6, lane = tid & 63;
  const int c = lane & 15, q = lane >> 4;
  char* B0  = LB[wave];
  char* B1  = LB[wave] + 8192;
  char* ACT = LB[wave] + 16384;
  const char* W = (const char*)wbuf;
  const int base = blockIdx.x * 32 + wave * 16;   // 16 timesteps per wave

  bf16x8 xf[2], af[8];

  // ---- X(states) -> regs, shared by actor-L1 and critic-L1 ----
  load_x_frags(states + (size_t)base * 64, c, q, xf);

  // ---- ACTOR(states) ----
  layer64(xf, W + OFF_AW1T * 2, ab1, ag1, an1, ACT, B0, B1, c, q, lane, af);
  layer256(af, W + OFF_AW2T * 2, ab2, ag2, an2, ACT, B0, B1, c, q, lane, af);
  {
    f32x4 p3[2];
    run_small<2>(af, W + OFF_AW3T * 2, B0, B1, c, q, lane, p3);
    softmax_write(p3, ab3, out, base, c, q);
  }

  // ---- CRITIC(states) ---- (xf still in regs)
  layer64(xf, W + OFF_CW1T * 2, cb1, cg1, cn1, ACT, B0, B1, c, q, lane, af);
  layer256(af, W + OFF_CW2T * 2, cb2, cg2, cn2, ACT, B0, B1, c, q, lane, af);
  float vst[4];
  {
    f32x4 v[1];
    run_small<1>(af, W + OFF_CW3T * 2, B0, B1, c, q, lane, v);
    const float b3 = cb3[0];
#pragma unroll
    for (int r = 0; r < 4; ++r) vst[r] = v[0][r] + b3;
  }

  // ---- CRITIC(next_states) ----
  load_x_frags(next_states + (size_t)base * 64, c, q, xf);
  layer64(xf, W + OFF_CW1T * 2, cb1, cg1, cn1, ACT, B0, B1, c, q, lane, af);
  layer256(af, W + OFF_CW2T * 2, cb2, cg2, cn2, ACT, B0, B1, c, q, lane, af);
  {
    f32x4 v[1];
    run_small<1>(af, W + OFF_CW3T * 2, B0, B1, c, q, lane, v);
    const float b3 = cb3[0];
    if (c == 0) {
#pragma unroll
      for (int r = 0; r < 4; ++r) {
        const int gr = base + q * 4 + r;
        const float nv = v[0][r] + b3;
        out[(size_t)gr * 20 + 19] = vst[r];   // stash value; gae -> return
        deltas[gr] = rewards[gr] + 0.99f * nv * masks[gr] - vst[r];
      }
    }
  }
}

// ---------------------------------------------------------------------------
// GAE, wave-parallel: each wave owns a 512-elem chunk + 512-elem lookahead.
// Truncation: GL^512 ~ 2e-14. value stashed at out[:,19] -> returns.
__global__ __launch_bounds__(256) void gae_kernel(
    const float* __restrict__ deltas, const float* __restrict__ masks,
    float* __restrict__ out) {
  const int w = (blockIdx.x * blockDim.x + threadIdx.x) >> 6;  // 0..1023
  const int lane = threadIdx.x & 63;
  const int idx0 = w * 512 + lane * 16;

  float d[16], cf[16];
  if (idx0 < T_SZ) {
#pragma unroll
    for (int i = 0; i < 4; ++i) {
      *(float4*)(d + i * 4)  = *(const float4*)(deltas + idx0 + i * 4);
      *(float4*)(cf + i * 4) = *(const float4*)(masks + idx0 + i * 4);
    }
#pragma unroll
    for (int i = 0; i < 16; ++i) cf[i] *= GL;
  } else {
#pragma unroll
    for (int i = 0; i < 16; ++i) { d[i] = 0.f; cf[i] = 0.f; }
  }

  float A = 0.f, P = 1.f;
#pragma unroll
  for (int i = 15; i >= 0; --i) { A = d[i] + cf[i] * A; P *= cf[i]; }

  float As = A, Ps = P;
#pragma unroll
  for (int st = 1; st < 64; st <<= 1) {
    float An = __shfl_down(As, st, 64);
    float Pn = __shfl_down(Ps, st, 64);
    if (lane + st < 64) { As = As + Ps * An; Ps = Ps * Pn; }
  }
  float G = __shfl_down(As, 1, 64);
  if (lane == 63) G = 0.f;

  if (lane < 32) {
    float g = G;
#pragma unroll
    for (int i = 15; i >= 0; --i) {
      g = d[i] + cf[i] * g;
      const size_t j = (size_t)(idx0 + i);
      float val = out[j * 20 + 19];
      out[j * 20 + 18] = g;
      out[j * 20 + 19] = g + val;
    }
  }
}

// ---------------------------------------------------------------------------
extern "C" void kernel_launch(void* const* d_in, const int* in_sizes, int n_in,
                              void* d_out, int out_size, void* d_ws, size_t ws_size,
                              hipStream_t stream) {
  const float* states      = (const float*)d_in[0];
  const float* next_states = (const float*)d_in[1];
  const float* rewards     = (const float*)d_in[2];
  const float* masks       = (const float*)d_in[3];
  const float* aw1 = (const float*)d_in[4];
  const float* ab1 = (const float*)d_in[5];
  const float* ag1 = (const float*)d_in[6];
  const float* an1 = (const float*)d_in[7];
  const float* aw2 = (const float*)d_in[8];
  const float* ab2 = (const float*)d_in[9];
  const float* ag2 = (const float*)d_in[10];
  const float* an2 = (const float*)d_in[11];
  const float* aw3 = (const float*)d_in[12];
  const float* ab3 = (const float*)d_in[13];
  const float* cw1 = (const float*)d_in[14];
  const float* cb1 = (const float*)d_in[15];
  const float* cg1 = (const float*)d_in[16];
  const float* cn1 = (const float*)d_in[17];
  const float* cw2 = (const float*)d_in[18];
  const float* cb2 = (const float*)d_in[19];
  const float* cg2 = (const float*)d_in[20];
  const float* cn2 = (const float*)d_in[21];
  const float* cw3 = (const float*)d_in[22];
  const float* cb3 = (const float*)d_in[23];

  __hip_bfloat16* wbuf = (__hip_bfloat16*)d_ws;
  float* deltas = (float*)((char*)d_ws + OFF_DELTAS_BYTES);
  float* out = (float*)d_out;

  prep_weights<<<(W_ELEMS + 255) / 256, 256, 0, stream>>>(aw1, aw2, aw3, cw1, cw2, cw3, wbuf);
  mlp_kernel<<<T_SZ / 32, 128, 0, stream>>>(
      states, next_states, rewards, masks,
      ab1, ag1, an1, ab2, ag2, an2, ab3,
      cb1, cg1, cn1, cb2, cg2, cn2, cb3,
      wbuf, deltas, out);
  gae_kernel<<<256, 256, 0, stream>>>(deltas, masks, out);
}

// Round 14
// 1110.252 us; speedup vs baseline: 2.8232x; 2.8232x over previous
//
#include <hip/hip_runtime.h>
#include <hip/hip_bf16.h>

// ============================================================================
// PPO agent fused forward (round 14):
//  r1-r13 invariant: every structure lands 2.1-3.3ms because each wave owns
//  16 rows -> every B-load feeds ONE MFMA, serial chain, 2 waves/SIMD.
//  This round changes the DATAFLOW: 2 row-tiles (32 rows) per wave, A in LDS.
//   - per ntile step: 1 B-load (1KB fragment-major) + 2 ds_read_b128 A-frags
//     + 2 MFMA -> exposed latency per MFMA halved; weight stream halved.
//   - A never in registers -> arch state ~70 regs (s/ss 16 + acc 8 + temps).
//   - LN: stash rows == C-layout rows -> stats stay lane-local; pass-2 is an
//     in-LDS RMW with NO broadcast shuffles. Next layer reads normalized LDS.
//   - X staged once per wave (4KB XB), reused by actor-L1 and critic-L1.
//   - no block barriers; sched_barrier(0) at layer edges only (r7 recipe);
//     nt-loop unroll capped to bound scheduler hoisting (anti-spill).
//  LDS 72KB/block (2 waves) -> 2 blocks/CU. Numerics: same rounding points
//  as r6/r13 (bf16 pre-LN stash) -> absmax ~0.125-0.25 < 0.34.
// ============================================================================

#define T_SZ 524288
#define GL 0.9405f   // GAMMA*LAM

typedef __attribute__((ext_vector_type(8))) short bf16x8;   // 8 bf16 (4 VGPRs)
typedef __attribute__((ext_vector_type(4))) float f32x4;

// ws layout (bf16 elements); weights in ntile/fragment-major layout (r13)
#define OFF_AW1T 0        // 256x64
#define OFF_AW2T 16384    // 256x256
#define OFF_AW3T 81920    // 32x256 (rows >=18 zero)
#define OFF_CW1T 90112    // 256x64
#define OFF_CW2T 106496   // 256x256
#define OFF_CW3T 172032   // 16x256 (rows >=1 zero)
#define W_ELEMS  176128
#define OFF_DELTAS_BYTES 352256

// k = p*32 + h*16 + w -> pos = p*32 + w*2 + h (applied to A and B alike)
__device__ __forceinline__ int perm_k(int k) {
  return (k & ~31) | ((k & 15) << 1) | ((k >> 4) & 1);
}

__device__ __forceinline__ unsigned pack2(float a, float b) {
  union { __hip_bfloat16 h; unsigned short u; } ua, ub;
  ua.h = __float2bfloat16(a); ub.h = __float2bfloat16(b);
  return (unsigned)ua.u | ((unsigned)ub.u << 16);
}

__device__ __forceinline__ void unpack2(unsigned u, float& a, float& b) {
  union { unsigned u; float f; } x, y;
  x.u = u << 16; y.u = u & 0xFFFF0000u;
  a = x.f; b = y.f;
}

// ---------------------------------------------------------------------------
// stage X: 32 rows x 64 fp32 -> k-permuted swizzled bf16 LDS [32][128B]
__device__ __forceinline__ void stage_x(const float* __restrict__ src,
                                        char* XB, int c, int q) {
#pragma unroll
  for (int t = 0; t < 2; ++t) {
    const int row = t * 16 + c;
    const float* rp = src + (size_t)row * 64;
#pragma unroll
    for (int ks = 0; ks < 2; ++ks) {
      float4 a = *(const float4*)(rp + ks * 32 + 4 * q);
      float4 b = *(const float4*)(rp + ks * 32 + 4 * q + 16);
      unsigned u[4];
      u[0] = pack2(a.x, b.x); u[1] = pack2(a.y, b.y);
      u[2] = pack2(a.z, b.z); u[3] = pack2(a.w, b.w);
      *(uint4*)(XB + row * 128 + ((ks * 64 + q * 16) ^ ((row & 7) << 4))) =
          *(uint4*)u;
    }
  }
}

// ---------------------------------------------------------------------------
// Linear(K->256)+bias+LN+ReLU for 2 row-tiles. A from LDS (astr bytes/row),
// B from global fragment-major. Pre-LN bf16 stash -> O; lane-local stats;
// pass-2 in-LDS RMW normalize+ReLU. O becomes next layer's A.
template<int K, int UNR>
__device__ __forceinline__ void layer2t(const char* A, int astr,
    const char* __restrict__ W,
    const float* __restrict__ bias, const float* __restrict__ gam,
    const float* __restrict__ bet, char* O, int c, int q, int lane) {
  constexpr int NK = K / 32;
  float s0[4] = {0, 0, 0, 0}, ss0[4] = {0, 0, 0, 0};
  float s1[4] = {0, 0, 0, 0}, ss1[4] = {0, 0, 0, 0};
  const int sw = (c & 7) << 4;           // (16+c)&7 == c&7
#pragma unroll UNR
  for (int nt = 0; nt < 16; ++nt) {
    const char* Wn = W + (size_t)nt * (K * 32);
    f32x4 acc0 = {0.f, 0.f, 0.f, 0.f}, acc1 = {0.f, 0.f, 0.f, 0.f};
#pragma unroll
    for (int ks = 0; ks < NK; ++ks) {
      bf16x8 b = *(const bf16x8*)(Wn + ks * 1024 + lane * 16);
      const int cb = (ks * 64 + q * 16) ^ sw;
      bf16x8 a0 = *(const bf16x8*)(A + (size_t)c * astr + cb);
      bf16x8 a1 = *(const bf16x8*)(A + (size_t)(16 + c) * astr + cb);
      acc0 = __builtin_amdgcn_mfma_f32_16x16x32_bf16(a0, b, acc0, 0, 0, 0);
      acc1 = __builtin_amdgcn_mfma_f32_16x16x32_bf16(a1, b, acc1, 0, 0, 0);
    }
    const float bb = bias[nt * 16 + c];
    const int kpn2 = (((nt >> 1) << 5) + (c << 1) + (nt & 1)) * 2;
#pragma unroll
    for (int r = 0; r < 4; ++r) {
      float v0 = acc0[r] + bb, v1 = acc1[r] + bb;
      s0[r] += v0; ss0[r] += v0 * v0;
      s1[r] += v1; ss1[r] += v1 * v1;
      const int rsw = ((q * 4 + r) & 7) << 4;   // same for row and row+16
      *(__hip_bfloat16*)(O + (q * 4 + r) * 512 + (kpn2 ^ rsw)) = __float2bfloat16(v0);
      *(__hip_bfloat16*)(O + (16 + q * 4 + r) * 512 + (kpn2 ^ rsw)) = __float2bfloat16(v1);
    }
  }
  // stats over the 16 c-lanes (lane = q*16+c; xor m<16 flips c only)
#pragma unroll
  for (int m = 1; m < 16; m <<= 1) {
#pragma unroll
    for (int r = 0; r < 4; ++r) {
      s0[r] += __shfl_xor(s0[r], m, 64); ss0[r] += __shfl_xor(ss0[r], m, 64);
      s1[r] += __shfl_xor(s1[r], m, 64); ss1[r] += __shfl_xor(ss1[r], m, 64);
    }
  }
#pragma unroll
  for (int r = 0; r < 4; ++r) {
    float mu0 = s0[r] * (1.f / 256.f);
    ss0[r] = rsqrtf(ss0[r] * (1.f / 256.f) - mu0 * mu0 + 1e-5f); s0[r] = mu0;
    float mu1 = s1[r] * (1.f / 256.f);
    ss1[r] = rsqrtf(ss1[r] * (1.f / 256.f) - mu1 * mu1 + 1e-5f); s1[r] = mu1;
  }
  // pass-2: in-LDS RMW normalize+ReLU (lane-local stats, own rows)
#pragma unroll
  for (int p = 0; p < 8; ++p) {
    const float g0 = gam[p * 32 + c],      b0v = bet[p * 32 + c];
    const float g1 = gam[p * 32 + 16 + c], b1v = bet[p * 32 + 16 + c];
#pragma unroll
    for (int r = 0; r < 4; ++r) {
      const int cb = (p * 64 + c * 4) ^ (((q * 4 + r) & 7) << 4);
      unsigned* ap0 = (unsigned*)(O + (q * 4 + r) * 512 + cb);
      unsigned* ap1 = (unsigned*)(O + (16 + q * 4 + r) * 512 + cb);
      float v0, v1;
      unpack2(*ap0, v0, v1);
      v0 = fmaxf((v0 - s0[r]) * ss0[r] * g0 + b0v, 0.f);
      v1 = fmaxf((v1 - s0[r]) * ss0[r] * g1 + b1v, 0.f);
      *ap0 = pack2(v0, v1);
      unpack2(*ap1, v0, v1);
      v0 = fmaxf((v0 - s1[r]) * ss1[r] * g0 + b0v, 0.f);
      v1 = fmaxf((v1 - s1[r]) * ss1[r] * g1 + b1v, 0.f);
      *ap1 = pack2(v0, v1);
    }
  }
}

// small final GEMM: NT ntiles, K=256, 2 row-tiles, A from LDS (stride 512)
template<int NT>
__device__ __forceinline__ void run_small2(const char* A,
    const char* __restrict__ W, int c, int q, int lane,
    f32x4* o0, f32x4* o1) {
  const int sw = (c & 7) << 4;
#pragma unroll
  for (int nt = 0; nt < NT; ++nt) {
    o0[nt] = (f32x4){0.f, 0.f, 0.f, 0.f};
    o1[nt] = (f32x4){0.f, 0.f, 0.f, 0.f};
  }
#pragma unroll
  for (int nt = 0; nt < NT; ++nt) {
    const char* Wn = W + (size_t)nt * 8192;
#pragma unroll
    for (int ks = 0; ks < 8; ++ks) {
      bf16x8 b = *(const bf16x8*)(Wn + ks * 1024 + lane * 16);
      const int cb = (ks * 64 + q * 16) ^ sw;
      bf16x8 a0 = *(const bf16x8*)(A + (size_t)c * 512 + cb);
      bf16x8 a1 = *(const bf16x8*)(A + (size_t)(16 + c) * 512 + cb);
      o0[nt] = __builtin_amdgcn_mfma_f32_16x16x32_bf16(a0, b, o0[nt], 0, 0, 0);
      o1[nt] = __builtin_amdgcn_mfma_f32_16x16x32_bf16(a1, b, o1[nt], 0, 0, 0);
    }
  }
}

__device__ __forceinline__ void softmax_write(f32x4* acc3,
    const float* __restrict__ ab3, float* __restrict__ out,
    int grow0, int c, int q) {
  float b0 = ab3[c];
  float b1 = (c < 2) ? ab3[16 + c] : 0.f;
#pragma unroll
  for (int r = 0; r < 4; ++r) {
    float x0 = acc3[0][r] + b0;
    float x1 = (c < 2) ? (acc3[1][r] + b1) : -1e30f;
    float mx = fmaxf(x0, x1);
#pragma unroll
    for (int m = 1; m < 16; m <<= 1) mx = fmaxf(mx, __shfl_xor(mx, m, 64));
    float e0 = __expf(x0 - mx);
    float e1 = (c < 2) ? __expf(x1 - mx) : 0.f;
    float sm = e0 + e1;
#pragma unroll
    for (int m = 1; m < 16; m <<= 1) sm += __shfl_xor(sm, m, 64);
    float inv = 1.f / sm;
    int gr = grow0 + q * 4 + r;
    out[(size_t)gr * 20 + c] = e0 * inv;
    if (c < 2) out[(size_t)gr * 20 + 16 + c] = e1 * inv;
  }
}

// ---------------------------------------------------------------------------
// prep: ntile/fragment-major (r13, verified). (n,k) of [N][K]:
// nt=n>>4, cc=n&15; kp=perm_k(k): ks=kp>>5, qq=(kp&31)>>3, e=kp&7
// -> elem = MO + nt*(16*K) + ks*512 + (qq*16+cc)*8 + e.
__device__ __forceinline__ int frag_idx(int mo, int K, int n, int k) {
  const int kp = perm_k(k);
  const int nt = n >> 4, cc = n & 15;
  const int ks = kp >> 5, w = kp & 31, qq = w >> 3, e = w & 7;
  return mo + nt * (16 * K) + ks * 512 + (qq * 16 + cc) * 8 + e;
}

__global__ void prep_weights(const float* __restrict__ aw1, const float* __restrict__ aw2,
                             const float* __restrict__ aw3, const float* __restrict__ cw1,
                             const float* __restrict__ cw2, const float* __restrict__ cw3,
                             __hip_bfloat16* __restrict__ wb) {
  int i = blockIdx.x * 256 + threadIdx.x;
  if (i >= W_ELEMS) return;
  float v; int dst;
  if (i < OFF_AW2T)      { int j = i;            int n = j >> 6, k = j & 63;  v = aw1[k * 256 + n];                 dst = frag_idx(OFF_AW1T, 64,  n, k); }
  else if (i < OFF_AW3T) { int j = i - OFF_AW2T; int n = j >> 8, k = j & 255; v = aw2[k * 256 + n];                 dst = frag_idx(OFF_AW2T, 256, n, k); }
  else if (i < OFF_CW1T) { int j = i - OFF_AW3T; int n = j >> 8, k = j & 255; v = (n < 18) ? aw3[k * 18 + n] : 0.f; dst = frag_idx(OFF_AW3T, 256, n, k); }
  else if (i < OFF_CW2T) { int j = i - OFF_CW1T; int n = j >> 6, k = j & 63;  v = cw1[k * 256 + n];                 dst = frag_idx(OFF_CW1T, 64,  n, k); }
  else if (i < OFF_CW3T) { int j = i - OFF_CW2T; int n = j >> 8, k = j & 255; v = cw2[k * 256 + n];                 dst = frag_idx(OFF_CW2T, 256, n, k); }
  else                   { int j = i - OFF_CW3T; int n = j >> 8, k = j & 255; v = (n == 0) ? cw3[k] : 0.f;          dst = frag_idx(OFF_CW3T, 256, n, k); }
  wb[dst] = __float2bfloat16(v);
}

// ---------------------------------------------------------------------------
__global__ __launch_bounds__(128, 2) void mlp_kernel(
    const float* __restrict__ states, const float* __restrict__ next_states,
    const float* __restrict__ rewards, const float* __restrict__ masks,
    const float* __restrict__ ab1, const float* __restrict__ ag1, const float* __restrict__ an1,
    const float* __restrict__ ab2, const float* __restrict__ ag2, const float* __restrict__ an2,
    const float* __restrict__ ab3,
    const float* __restrict__ cb1, const float* __restrict__ cg1, const float* __restrict__ cn1,
    const float* __restrict__ cb2, const float* __restrict__ cg2, const float* __restrict__ cn2,
    const float* __restrict__ cb3,
    const __hip_bfloat16* __restrict__ wbuf,
    float* __restrict__ deltas, float* __restrict__ out) {
  __shared__ char LB[2][36864];       // per wave: XB 4K | A0 16K | A1 16K
  const int tid = threadIdx.x;
  const int wave = tid >> 6, lane = tid & 63;
  const int c = lane & 15, q = lane >> 4;
  char* XB = LB[wave];
  char* A0 = LB[wave] + 4096;
  char* A1 = LB[wave] + 4096 + 16384;
  const char* W = (const char*)wbuf;
  const int base = blockIdx.x * 64 + wave * 32;   // 32 timesteps per wave

  // ---- X(states) staged once (actor-L1 + critic-L1 share it) ----
  stage_x(states + (size_t)base * 64, XB, c, q);

  // ---- ACTOR(states) ----
  layer2t<64, 4>(XB, 128, W + OFF_AW1T * 2, ab1, ag1, an1, A0, c, q, lane);
  __builtin_amdgcn_sched_barrier(0);
  layer2t<256, 2>(A0, 512, W + OFF_AW2T * 2, ab2, ag2, an2, A1, c, q, lane);
  __builtin_amdgcn_sched_barrier(0);
  {
    f32x4 p0[2], p1[2];
    run_small2<2>(A1, W + OFF_AW3T * 2, c, q, lane, p0, p1);
    softmax_write(p0, ab3, out, base, c, q);
    softmax_write(p1, ab3, out, base + 16, c, q);
  }
  __builtin_amdgcn_sched_barrier(0);

  // ---- CRITIC(states) ---- (XB still intact)
  layer2t<64, 4>(XB, 128, W + OFF_CW1T * 2, cb1, cg1, cn1, A0, c, q, lane);
  __builtin_amdgcn_sched_barrier(0);
  layer2t<256, 2>(A0, 512, W + OFF_CW2T * 2, cb2, cg2, cn2, A1, c, q, lane);
  __builtin_amdgcn_sched_barrier(0);
  float vst0[4], vst1[4];
  {
    f32x4 v0[1], v1[1];
    run_small2<1>(A1, W + OFF_CW3T * 2, c, q, lane, v0, v1);
    const float b3 = cb3[0];
#pragma unroll
    for (int r = 0; r < 4; ++r) { vst0[r] = v0[0][r] + b3; vst1[r] = v1[0][r] + b3; }
  }
  __builtin_amdgcn_sched_barrier(0);

  // ---- CRITIC(next_states) ----
  stage_x(next_states + (size_t)base * 64, XB, c, q);
  layer2t<64, 4>(XB, 128, W + OFF_CW1T * 2, cb1, cg1, cn1, A0, c, q, lane);
  __builtin_amdgcn_sched_barrier(0);
  layer2t<256, 2>(A0, 512, W + OFF_CW2T * 2, cb2, cg2, cn2, A1, c, q, lane);
  __builtin_amdgcn_sched_barrier(0);
  {
    f32x4 v0[1], v1[1];
    run_small2<1>(A1, W + OFF_CW3T * 2, c, q, lane, v0, v1);
    const float b3 = cb3[0];
    if (c == 0) {
#pragma unroll
      for (int r = 0; r < 4; ++r) {
        const int g0 = base + q * 4 + r;
        const int g1 = base + 16 + q * 4 + r;
        const float nv0 = v0[0][r] + b3;
        const float nv1 = v1[0][r] + b3;
        out[(size_t)g0 * 20 + 19] = vst0[r];   // stash value; gae -> return
        out[(size_t)g1 * 20 + 19] = vst1[r];
        deltas[g0] = rewards[g0] + 0.99f * nv0 * masks[g0] - vst0[r];
        deltas[g1] = rewards[g1] + 0.99f * nv1 * masks[g1] - vst1[r];
      }
    }
  }
}

// ---------------------------------------------------------------------------
// GAE, wave-parallel: each wave owns a 512-elem chunk + 512-elem lookahead.
// Truncation: GL^512 ~ 2e-14. value stashed at out[:,19] -> returns.
__global__ __launch_bounds__(256) void gae_kernel(
    const float* __restrict__ deltas, const float* __restrict__ masks,
    float* __restrict__ out) {
  const int w = (blockIdx.x * blockDim.x + threadIdx.x) >> 6;  // 0..1023
  const int lane = threadIdx.x & 63;
  const int idx0 = w * 512 + lane * 16;

  float d[16], cf[16];
  if (idx0 < T_SZ) {
#pragma unroll
    for (int i = 0; i < 4; ++i) {
      *(float4*)(d + i * 4)  = *(const float4*)(deltas + idx0 + i * 4);
      *(float4*)(cf + i * 4) = *(const float4*)(masks + idx0 + i * 4);
    }
#pragma unroll
    for (int i = 0; i < 16; ++i) cf[i] *= GL;
  } else {
#pragma unroll
    for (int i = 0; i < 16; ++i) { d[i] = 0.f; cf[i] = 0.f; }
  }

  float A = 0.f, P = 1.f;
#pragma unroll
  for (int i = 15; i >= 0; --i) { A = d[i] + cf[i] * A; P *= cf[i]; }

  float As = A, Ps = P;
#pragma unroll
  for (int st = 1; st < 64; st <<= 1) {
    float An = __shfl_down(As, st, 64);
    float Pn = __shfl_down(Ps, st, 64);
    if (lane + st < 64) { As = As + Ps * An; Ps = Ps * Pn; }
  }
  float G = __shfl_down(As, 1, 64);
  if (lane == 63) G = 0.f;

  if (lane < 32) {
    float g = G;
#pragma unroll
    for (int i = 15; i >= 0; --i) {
      g = d[i] + cf[i] * g;
      const size_t j = (size_t)(idx0 + i);
      float val = out[j * 20 + 19];
      out[j * 20 + 18] = g;
      out[j * 20 + 19] = g + val;
    }
  }
}

// ---------------------------------------------------------------------------
extern "C" void kernel_launch(void* const* d_in, const int* in_sizes, int n_in,
                              void* d_out, int out_size, void* d_ws, size_t ws_size,
                              hipStream_t stream) {
  const float* states      = (const float*)d_in[0];
  const float* next_states = (const float*)d_in[1];
  const float* rewards     = (const float*)d_in[2];
  const float* masks       = (const float*)d_in[3];
  const float* aw1 = (const float*)d_in[4];
  const float* ab1 = (const float*)d_in[5];
  const float* ag1 = (const float*)d_in[6];
  const float* an1 = (const float*)d_in[7];
  const float* aw2 = (const float*)d_in[8];
  const float* ab2 = (const float*)d_in[9];
  const float* ag2 = (const float*)d_in[10];
  const float* an2 = (const float*)d_in[11];
  const float* aw3 = (const float*)d_in[12];
  const float* ab3 = (const float*)d_in[13];
  const float* cw1 = (const float*)d_in[14];
  const float* cb1 = (const float*)d_in[15];
  const float* cg1 = (const float*)d_in[16];
  const float* cn1 = (const float*)d_in[17];
  const float* cw2 = (const float*)d_in[18];
  const float* cb2 = (const float*)d_in[19];
  const float* cg2 = (const float*)d_in[20];
  const float* cn2 = (const float*)d_in[21];
  const float* cw3 = (const float*)d_in[22];
  const float* cb3 = (const float*)d_in[23];

  __hip_bfloat16* wbuf = (__hip_bfloat16*)d_ws;
  float* deltas = (float*)((char*)d_ws + OFF_DELTAS_BYTES);
  float* out = (float*)d_out;

  prep_weights<<<(W_ELEMS + 255) / 256, 256, 0, stream>>>(aw1, aw2, aw3, cw1, cw2, cw3, wbuf);
  mlp_kernel<<<T_SZ / 64, 128, 0, stream>>>(
      states, next_states, rewards, masks,
      ab1, ag1, an1, ab2, ag2, an2, ab3,
      cb1, cg1, cn1, cb2, cg2, cn2, cb3,
      wbuf, deltas, out);
  gae_kernel<<<256, 256, 0, stream>>>(deltas, masks, out);
}